// Round 21
// baseline (52.180 us; speedup 1.0000x reference)
//
#include <hip/hip_runtime.h>
#include <hip/hip_bf16.h>

#define NN 4096
#define IN_DIM 512
#define OUT_DIM 256
#define NH 4
#define HD 64
#define NEG_SLOPE 0.2f
#define LN_EPS 1e-5f
#define LOG2E 1.4426950408889634f
#define MDC 8.0f   // constant softmax stabilizer (log2 domain); valid upper bound

typedef __attribute__((ext_vector_type(8))) short short8;
typedef __attribute__((ext_vector_type(4))) float f32x4;
typedef unsigned short u16;
typedef unsigned int u32;
typedef unsigned char u8;

// ---------------------------------------------------------------------------
// K1: MFMA projection with ALL-LDS operands + in-block W transpose + adj->mask
// pack via wave specialization. [round-20 verified]
// ---------------------------------------------------------------------------
__global__ __launch_bounds__(512) void k1_proj(
    const float* __restrict__ x, const float* __restrict__ W,
    const float* __restrict__ a, const int* __restrict__ adj,
    u16* __restrict__ WxT,
    float* __restrict__ s_src,
    float* __restrict__ d_dst,
    u8* __restrict__ mask)
{
  const int h = blockIdx.x & 3;
  const int i0 = (blockIdx.x >> 2) * 64;
  const int t = threadIdx.x;
  const int wv = t >> 6;
  const int lane = t & 63;
  const int rloc = lane & 15;
  const int g = lane >> 4;

  __shared__ u16 xl[64 * 512];   // 64 KiB: x rows i0..i0+63, swizzled units
  __shared__ u16 wl[64 * 512];   // 64 KiB: W^T rows d=0..63, swizzled units

#pragma unroll
  for (int p = 0; p < 8; ++p) {
    const int n = p * 512 + t;
    const int r = n >> 6;
    const int u = n & 63;
    const int phys = (u & 56) | ((u & 7) ^ (r & 7));
    const float* xr = x + (size_t)(i0 + r) * IN_DIM + u * 8;
    const float4 lo = *reinterpret_cast<const float4*>(xr);
    const float4 hi = *reinterpret_cast<const float4*>(xr + 4);
    const float fv[8] = {lo.x, lo.y, lo.z, lo.w, hi.x, hi.y, hi.z, hi.w};
    u16 us[8];
#pragma unroll
    for (int e = 0; e < 8; ++e) {
      __hip_bfloat16 bv = __float2bfloat16(fv[e]);
      us[e] = *reinterpret_cast<const u16*>(&bv);
    }
    uint4 pk;
    pk.x = (u32)us[0] | ((u32)us[1] << 16);
    pk.y = (u32)us[2] | ((u32)us[3] << 16);
    pk.z = (u32)us[4] | ((u32)us[5] << 16);
    pk.w = (u32)us[6] | ((u32)us[7] << 16);
    *reinterpret_cast<uint4*>(&xl[r * 512 + phys * 8]) = pk;
  }

  {
#pragma unroll
    for (int u0 = 0; u0 < 8; ++u0) {
      const int ub = wv * 8 + u0;
      u16 us[8];
#pragma unroll
      for (int e = 0; e < 8; ++e) {
        const float wf = W[((size_t)h * IN_DIM + ub * 8 + e) * HD + lane];
        __hip_bfloat16 bv = __float2bfloat16(wf);
        us[e] = *reinterpret_cast<const u16*>(&bv);
      }
      const int phys = (ub & 56) | ((ub & 7) ^ (lane & 7));
      uint4 pk;
      pk.x = (u32)us[0] | ((u32)us[1] << 16);
      pk.y = (u32)us[2] | ((u32)us[3] << 16);
      pk.z = (u32)us[4] | ((u32)us[5] << 16);
      pk.w = (u32)us[6] | ((u32)us[7] << 16);
      *reinterpret_cast<uint4*>(&wl[lane * 512 + phys * 8]) = pk;
    }
  }
  __syncthreads();

  if (wv >= 4) {
    const int t2 = t - 256;
    const int j0 = t2 * 16;
    const int prow0 = i0 + h * 16;
#pragma unroll
    for (int rr = 0; rr < 16; ++rr) {
      const int row = prow0 + rr;
      const int* ap = adj + (size_t)row * NN + j0;
      u32 bb = 0;
#pragma unroll
      for (int q = 0; q < 4; ++q) {
        const int4 v = *reinterpret_cast<const int4*>(ap + q * 4);
        const int vj = j0 + q * 4;
        if ((v.x > 0) || (row == vj))     bb |= 1u << (q * 4);
        if ((v.y > 0) || (row == vj + 1)) bb |= 1u << (q * 4 + 1);
        if ((v.z > 0) || (row == vj + 2)) bb |= 1u << (q * 4 + 2);
        if ((v.w > 0) || (row == vj + 3)) bb |= 1u << (q * 4 + 3);
      }
      *reinterpret_cast<u16*>(mask + (size_t)row * (NN / 8) + t2 * 2) = (u16)bb;
    }
    return;
  }

  const int rbase = wv * 16;
  f32x4 acc[4] = {};
#pragma unroll
  for (int ks = 0; ks < 16; ++ks) {
    const int u = ks * 4 + g;
    const int ar = rbase + rloc;
    const int aphys = (u & 56) | ((u & 7) ^ (ar & 7));
    const short8 af = *reinterpret_cast<const short8*>(&xl[ar * 512 + aphys * 8]);
#pragma unroll
    for (int dt = 0; dt < 4; ++dt) {
      const int br = dt * 16 + rloc;
      const int bphys = (u & 56) | ((u & 7) ^ (br & 7));
      const short8 bf = *reinterpret_cast<const short8*>(&wl[br * 512 + bphys * 8]);
      acc[dt] = __builtin_amdgcn_mfma_f32_16x16x32_bf16(af, bf, acc[dt], 0, 0, 0);
    }
  }

#pragma unroll
  for (int dt = 0; dt < 4; ++dt) {
    u16 us[4];
#pragma unroll
    for (int q = 0; q < 4; ++q) {
      __hip_bfloat16 bv = __float2bfloat16(acc[dt][q]);
      us[q] = *reinterpret_cast<const u16*>(&bv);
    }
    ushort4 pk = {us[0], us[1], us[2], us[3]};
    *reinterpret_cast<ushort4*>(
        WxT + (size_t)(h * HD + dt * 16 + rloc) * NN + i0 + rbase + g * 4) = pk;
  }

  float as_v[4], ad_v[4];
#pragma unroll
  for (int dt = 0; dt < 4; ++dt) {
    as_v[dt] = a[(size_t)h * 2 * HD + dt * 16 + rloc];
    ad_v[dt] = a[(size_t)h * 2 * HD + HD + dt * 16 + rloc];
  }
  float sv[4], dv[4];
#pragma unroll
  for (int q = 0; q < 4; ++q) {
    float s = 0.f, d = 0.f;
#pragma unroll
    for (int dt = 0; dt < 4; ++dt) {
      s = fmaf(acc[dt][q], as_v[dt], s);
      d = fmaf(acc[dt][q], ad_v[dt], d);
    }
    sv[q] = s; dv[q] = d;
  }
#pragma unroll
  for (int mm = 8; mm >= 1; mm >>= 1) {
#pragma unroll
    for (int q = 0; q < 4; ++q) {
      sv[q] += __shfl_xor(sv[q], mm);
      dv[q] += __shfl_xor(dv[q], mm);
    }
  }
  if (rloc == 0) {
#pragma unroll
    for (int q = 0; q < 4; ++q) {
      const int i = i0 + rbase + g * 4 + q;
      s_src[(size_t)h * NN + i] = sv[q] * LOG2E;
      d_dst[(size_t)h * NN + i] = dv[q] * LOG2E;
    }
  }
}

// ---------------------------------------------------------------------------
// K3: masked rank-1 softmax via block-local E-tables (LDS) + PV (bf16 MFMA),
// LDS-staged & double-buffered. NEW GEOMETRY for LDS-pipe relief: block = 256
// threads (4 waves), wave owns 64 rows = 4 row-sets -> each bfr/E ds_read
// feeds 4 A-fragments (2x reuse vs r15's 2 row-sets). Same 76 KB LDS, same
// grid (16,4,4), per-row math bit-identical to the verified r15 kernel.
// launch_bounds(256,2): VGPR cap 256 >> ~170 live (r16 lesson respected).
// ---------------------------------------------------------------------------
__global__ __launch_bounds__(256, 2) void k3_attn(
    const u8* __restrict__ mask,
    const u16* __restrict__ WxT,
    const float* __restrict__ s_src, const float* __restrict__ d_dst,
    u16* __restrict__ Pp, float* __restrict__ Sp)
{
  const int bx = blockIdx.x;
  const int h = blockIdx.y;
  const int jq = blockIdx.z;
  const int t = threadIdx.x;
  const int wv = t >> 6;          // 0..3
  const int lane = t & 63;
  const int rloc = lane & 15;
  const int g = lane >> 4;
  const int i_base = bx * 256 + wv * 64;   // wave owns 64 rows

  __shared__ u16 wt[2][64 * 128];   // 32 KiB, XOR-swizzled
  __shared__ u32 mk[256 * 36];      // 36 KiB
  __shared__ float el[1024 * 2];    // 8 KiB

  // ---- per-row-set softmax constants (4 sets of 16 rows) ----
  float c1[4], c2[4];
#pragma unroll
  for (int s = 0; s < 4; ++s) {
    const float si = s_src[(size_t)h * NN + i_base + s * 16 + rloc];
    const float e0 = si + MDC;
    const float m = fmaxf(e0, NEG_SLOPE * e0);
    const float sa = si - m;
    const float sb = fmaf(NEG_SLOPE, si, -m);
    float v1, v2;
    asm("v_exp_f32 %0, %1" : "=v"(v1) : "v"(sa));
    asm("v_exp_f32 %0, %1" : "=v"(v2) : "v"(sb));
    c1[s] = v1; c2[s] = v2;
  }

  const u16* wsrc = WxT + (size_t)(h * HD) * NN + jq * 1024;

  const int r0 = t >> 4;           // 0..15
  const int un = t & 15;
  const int up = un ^ (r0 & 7);    // same swizzle for rows r0+16k (16k%8==0)

  // ---- prologue: E-table gen + mask + WxT tile 0 (256 threads) ----
#pragma unroll
  for (int p = 0; p < 4; ++p) {
    const int j = p * 256 + t;
    const float dj = d_dst[(size_t)h * NN + jq * 1024 + j];
    const float djs = dj * NEG_SLOPE;
    float e1, e2;
    asm("v_exp_f32 %0, %1" : "=v"(e1) : "v"(dj));
    asm("v_exp_f32 %0, %1" : "=v"(e2) : "v"(djs));
    el[j * 2] = e1;
    el[j * 2 + 1] = e2;
  }
#pragma unroll
  for (int k = 0; k < 8; ++k) {
    const int n = k * 256 + t;
    const int row = n >> 3;
    const int quad = n & 7;
    const uint4 mv = *reinterpret_cast<const uint4*>(
        mask + ((size_t)(bx * 256 + row) * (NN / 8)) + jq * 128 + quad * 16);
    *reinterpret_cast<uint4*>(&mk[row * 36 + quad * 4]) = mv;
  }
#pragma unroll
  for (int k = 0; k < 4; ++k) {
    const int rr = r0 + k * 16;
    const uint4 sv = *reinterpret_cast<const uint4*>(wsrc + (size_t)rr * NN + un * 8);
    *reinterpret_cast<uint4*>(&wt[0][rr * 128 + up * 8]) = sv;
  }
  __syncthreads();

  f32x4 acc[4][4] = {};   // [row-set][dt]
  f32x4 accs[4] = {};     // row sums per set
  short8 ones;
#pragma unroll
  for (int e = 0; e < 8; ++e) ones[e] = (short)0x3F80;

  int buf = 0;
  for (int tile = 0; tile < 8; ++tile) {
    uint4 n0, n1, n2, n3;
    const bool pf = (tile < 7);
    if (pf) {
      n0 = *reinterpret_cast<const uint4*>(
          wsrc + (size_t)r0 * NN + (tile + 1) * 128 + un * 8);
      n1 = *reinterpret_cast<const uint4*>(
          wsrc + (size_t)(r0 + 16) * NN + (tile + 1) * 128 + un * 8);
      n2 = *reinterpret_cast<const uint4*>(
          wsrc + (size_t)(r0 + 32) * NN + (tile + 1) * 128 + un * 8);
      n3 = *reinterpret_cast<const uint4*>(
          wsrc + (size_t)(r0 + 48) * NN + (tile + 1) * 128 + un * 8);
    }

    uint4 mq[4];
#pragma unroll
    for (int s = 0; s < 4; ++s)
      mq[s] = *reinterpret_cast<const uint4*>(
          &mk[(wv * 64 + s * 16 + rloc) * 36 + tile * 4]);

#pragma unroll
    for (int ks = 0; ks < 4; ++ks) {
      short8 bfr[4];
#pragma unroll
      for (int dt = 0; dt < 4; ++dt) {
        const int row = dt * 16 + rloc;
        const int unit = (ks * 4 + g) ^ (row & 7);
        bfr[dt] = *reinterpret_cast<const short8*>(&wt[buf][row * 128 + unit * 8]);
      }
      const int jloc = tile * 128 + ks * 32 + g * 8;
      const float* eb = &el[2 * jloc];
      const float4 Ea = *reinterpret_cast<const float4*>(eb);
      const float4 Eb = *reinterpret_cast<const float4*>(eb + 4);
      const float4 Ec = *reinterpret_cast<const float4*>(eb + 8);
      const float4 Ed = *reinterpret_cast<const float4*>(eb + 12);
      const float E1v[8] = {Ea.x, Ea.z, Eb.x, Eb.z, Ec.x, Ec.z, Ed.x, Ed.z};
      const float E2v[8] = {Ea.y, Ea.w, Eb.y, Eb.w, Ec.y, Ec.w, Ed.y, Ed.w};

#pragma unroll
      for (int s = 0; s < 4; ++s) {
        const u32 mw = (ks == 0) ? mq[s].x : (ks == 1) ? mq[s].y
                     : (ks == 2) ? mq[s].z : mq[s].w;
        const u32 mb = (mw >> (g * 8)) & 0xffu;
        short8 af;
#pragma unroll
        for (int e = 0; e < 8; ++e) {
          float pv = fmaxf(c1[s] * E1v[e], c2[s] * E2v[e]);
          pv = (mb & (1u << e)) ? pv : 0.f;
          __hip_bfloat16 bb = __float2bfloat16(pv);
          af[e] = *reinterpret_cast<const short*>(&bb);
        }
#pragma unroll
        for (int dt = 0; dt < 4; ++dt)
          acc[s][dt] = __builtin_amdgcn_mfma_f32_16x16x32_bf16(af, bfr[dt], acc[s][dt], 0, 0, 0);
        accs[s] = __builtin_amdgcn_mfma_f32_16x16x32_bf16(af, ones, accs[s], 0, 0, 0);
      }
    }

    if (pf) {
      *reinterpret_cast<uint4*>(&wt[buf ^ 1][r0 * 128 + up * 8]) = n0;
      *reinterpret_cast<uint4*>(&wt[buf ^ 1][(r0 + 16) * 128 + up * 8]) = n1;
      *reinterpret_cast<uint4*>(&wt[buf ^ 1][(r0 + 32) * 128 + up * 8]) = n2;
      *reinterpret_cast<uint4*>(&wt[buf ^ 1][(r0 + 48) * 128 + up * 8]) = n3;
    }
    __syncthreads();
    buf ^= 1;
  }

  // ---- epilogue: bf16 partial tiles + row sums ----
  u16* Pb = Pp + (size_t)jq * NN * OUT_DIM;
#pragma unroll
  for (int s = 0; s < 4; ++s) {
#pragma unroll
    for (int dt = 0; dt < 4; ++dt)
#pragma unroll
      for (int q = 0; q < 4; ++q) {
        __hip_bfloat16 v = __float2bfloat16(acc[s][dt][q]);
        Pb[(size_t)(i_base + s * 16 + g * 4 + q) * OUT_DIM + h * HD + dt * 16 + rloc] =
            *reinterpret_cast<const u16*>(&v);
      }
    if (rloc == 0)
      *reinterpret_cast<f32x4*>(
          &Sp[((size_t)jq * NH + h) * NN + i_base + s * 16 + g * 4]) = accs[s];
  }
}

// ---------------------------------------------------------------------------
// K4: merge 4 j-quarter partials, normalize, ELU, LayerNorm, store.
// [round-7 verified]
// ---------------------------------------------------------------------------
__global__ __launch_bounds__(256) void k4_final(
    const u16* __restrict__ Pp, const float* __restrict__ Sp,
    const float* __restrict__ gamma, const float* __restrict__ beta,
    float* __restrict__ out)
{
  const int i0 = blockIdx.x * 16;
  const int t = threadIdx.x;
  const int wv = t >> 6;
  const int lane = t & 63;
  const int c0 = lane * 4;
  const int h = lane >> 4;

  const float4 gm = *reinterpret_cast<const float4*>(gamma + c0);
  const float4 bt = *reinterpret_cast<const float4*>(beta + c0);

  for (int rr = 0; rr < 4; ++rr) {
    const int i = i0 + wv * 4 + rr;
    float v[4] = {0.f, 0.f, 0.f, 0.f};
    float denom = 0.f;
#pragma unroll
    for (int q = 0; q < 4; ++q) {
      const ushort4 pv = *reinterpret_cast<const ushort4*>(
          Pp + (size_t)q * NN * OUT_DIM + (size_t)i * OUT_DIM + c0);
      v[0] += __uint_as_float((u32)pv.x << 16);
      v[1] += __uint_as_float((u32)pv.y << 16);
      v[2] += __uint_as_float((u32)pv.z << 16);
      v[3] += __uint_as_float((u32)pv.w << 16);
      denom += Sp[((size_t)q * NH + h) * NN + i];
    }
    const float inv = 1.f / denom;
    float sum = 0.f, sq = 0.f;
#pragma unroll
    for (int q2 = 0; q2 < 4; ++q2) {
      float xx = v[q2] * inv;
      xx = (xx > 0.f) ? xx : expm1f(xx);
      v[q2] = xx;
      sum += xx;
      sq += xx * xx;
    }
#pragma unroll
    for (int mm = 32; mm >= 1; mm >>= 1) {
      sum += __shfl_xor(sum, mm);
      sq += __shfl_xor(sq, mm);
    }
    const float mu = sum * (1.f / OUT_DIM);
    const float var = sq * (1.f / OUT_DIM) - mu * mu;
    const float rs = rsqrtf(var + LN_EPS);
    float4 o;
    o.x = (v[0] - mu) * rs * gm.x + bt.x;
    o.y = (v[1] - mu) * rs * gm.y + bt.y;
    o.z = (v[2] - mu) * rs * gm.z + bt.z;
    o.w = (v[3] - mu) * rs * gm.w + bt.w;
    *reinterpret_cast<float4*>(out + (size_t)i * OUT_DIM + c0) = o;
  }
}

extern "C" void kernel_launch(void* const* d_in, const int* in_sizes, int n_in,
                              void* d_out, int out_size, void* d_ws, size_t ws_size,
                              hipStream_t stream) {
  const float* x = (const float*)d_in[0];
  const int* adj = (const int*)d_in[1];
  const float* W = (const float*)d_in[2];
  const float* a = (const float*)d_in[3];
  const float* gamma = (const float*)d_in[4];
  const float* beta = (const float*)d_in[5];
  float* out = (float*)d_out;

  char* ws = (char*)d_ws;
  size_t off = 0;
  u16* WxT = (u16*)(ws + off);        off += (size_t)NH * HD * NN * 2;          // 2 MiB
  float* s_src = (float*)(ws + off);  off += (size_t)NH * NN * 4;               // 64 KiB
  float* d_dst = (float*)(ws + off);  off += (size_t)NH * NN * 4;               // 64 KiB
  u8* mask = (u8*)(ws + off);         off += (size_t)NN * (NN / 8);             // 2 MiB
  u16* Pp = (u16*)(ws + off);         off += (size_t)4 * NN * OUT_DIM * 2;      // 8 MiB (bf16)
  float* Sp = (float*)(ws + off);     off += (size_t)4 * NH * NN * 4;           // 256 KiB

  k1_proj<<<dim3(256), dim3(512), 0, stream>>>(x, W, a, adj, WxT, s_src,
                                               d_dst, mask);
  k3_attn<<<dim3(16, NH, 4), dim3(256), 0, stream>>>(mask, WxT, s_src, d_dst,
                                                     Pp, Sp);
  k4_final<<<dim3(256), dim3(256), 0, stream>>>(Pp, Sp, gamma, beta, out);
}

// Round 22
// 50.352 us; speedup vs baseline: 1.0363x; 1.0363x over previous
//
#include <hip/hip_runtime.h>
#include <hip/hip_bf16.h>

#define NN 4096
#define IN_DIM 512
#define OUT_DIM 256
#define NH 4
#define HD 64
#define NEG_SLOPE 0.2f
#define LN_EPS 1e-5f
#define LOG2E 1.4426950408889634f
#define MDC 8.0f   // constant softmax stabilizer (log2 domain); valid upper bound

typedef __attribute__((ext_vector_type(8))) short short8;
typedef __attribute__((ext_vector_type(4))) float f32x4;
typedef unsigned short u16;
typedef unsigned int u32;
typedef unsigned char u8;

// ---------------------------------------------------------------------------
// K1: MFMA projection with ALL-LDS operands + in-block W transpose + adj->mask
// pack via wave specialization. grid 256 = (64-row i-tile = bx>>2, head h =
// bx&3), block 512 = 8 waves: waves 0-3 compute (16 rows each, head h, A and
// B both from LDS); waves 4-7 pack rows i0+h*16..+16 (1x coverage across the
// 4 head-blocks of each tile). [round-20 verified best]
// ---------------------------------------------------------------------------
__global__ __launch_bounds__(512) void k1_proj(
    const float* __restrict__ x, const float* __restrict__ W,
    const float* __restrict__ a, const int* __restrict__ adj,
    u16* __restrict__ WxT,
    float* __restrict__ s_src,
    float* __restrict__ d_dst,
    u8* __restrict__ mask)
{
  const int h = blockIdx.x & 3;
  const int i0 = (blockIdx.x >> 2) * 64;
  const int t = threadIdx.x;
  const int wv = t >> 6;
  const int lane = t & 63;
  const int rloc = lane & 15;
  const int g = lane >> 4;

  __shared__ u16 xl[64 * 512];   // 64 KiB: x rows i0..i0+63, swizzled units
  __shared__ u16 wl[64 * 512];   // 64 KiB: W^T rows d=0..63, swizzled units

#pragma unroll
  for (int p = 0; p < 8; ++p) {
    const int n = p * 512 + t;
    const int r = n >> 6;
    const int u = n & 63;
    const int phys = (u & 56) | ((u & 7) ^ (r & 7));
    const float* xr = x + (size_t)(i0 + r) * IN_DIM + u * 8;
    const float4 lo = *reinterpret_cast<const float4*>(xr);
    const float4 hi = *reinterpret_cast<const float4*>(xr + 4);
    const float fv[8] = {lo.x, lo.y, lo.z, lo.w, hi.x, hi.y, hi.z, hi.w};
    u16 us[8];
#pragma unroll
    for (int e = 0; e < 8; ++e) {
      __hip_bfloat16 bv = __float2bfloat16(fv[e]);
      us[e] = *reinterpret_cast<const u16*>(&bv);
    }
    uint4 pk;
    pk.x = (u32)us[0] | ((u32)us[1] << 16);
    pk.y = (u32)us[2] | ((u32)us[3] << 16);
    pk.z = (u32)us[4] | ((u32)us[5] << 16);
    pk.w = (u32)us[6] | ((u32)us[7] << 16);
    *reinterpret_cast<uint4*>(&xl[r * 512 + phys * 8]) = pk;
  }

  {
#pragma unroll
    for (int u0 = 0; u0 < 8; ++u0) {
      const int ub = wv * 8 + u0;            // 16B-unit index = k/8
      u16 us[8];
#pragma unroll
      for (int e = 0; e < 8; ++e) {
        const float wf = W[((size_t)h * IN_DIM + ub * 8 + e) * HD + lane];
        __hip_bfloat16 bv = __float2bfloat16(wf);
        us[e] = *reinterpret_cast<const u16*>(&bv);
      }
      const int phys = (ub & 56) | ((ub & 7) ^ (lane & 7));
      uint4 pk;
      pk.x = (u32)us[0] | ((u32)us[1] << 16);
      pk.y = (u32)us[2] | ((u32)us[3] << 16);
      pk.z = (u32)us[4] | ((u32)us[5] << 16);
      pk.w = (u32)us[6] | ((u32)us[7] << 16);
      *reinterpret_cast<uint4*>(&wl[lane * 512 + phys * 8]) = pk;
    }
  }
  __syncthreads();

  if (wv >= 4) {
    const int t2 = t - 256;
    const int j0 = t2 * 16;
    const int prow0 = i0 + h * 16;
#pragma unroll
    for (int rr = 0; rr < 16; ++rr) {
      const int row = prow0 + rr;
      const int* ap = adj + (size_t)row * NN + j0;
      u32 bb = 0;
#pragma unroll
      for (int q = 0; q < 4; ++q) {
        const int4 v = *reinterpret_cast<const int4*>(ap + q * 4);
        const int vj = j0 + q * 4;
        if ((v.x > 0) || (row == vj))     bb |= 1u << (q * 4);
        if ((v.y > 0) || (row == vj + 1)) bb |= 1u << (q * 4 + 1);
        if ((v.z > 0) || (row == vj + 2)) bb |= 1u << (q * 4 + 2);
        if ((v.w > 0) || (row == vj + 3)) bb |= 1u << (q * 4 + 3);
      }
      *reinterpret_cast<u16*>(mask + (size_t)row * (NN / 8) + t2 * 2) = (u16)bb;
    }
    return;
  }

  const int rbase = wv * 16;
  f32x4 acc[4] = {};
#pragma unroll
  for (int ks = 0; ks < 16; ++ks) {
    const int u = ks * 4 + g;
    const int ar = rbase + rloc;
    const int aphys = (u & 56) | ((u & 7) ^ (ar & 7));
    const short8 af = *reinterpret_cast<const short8*>(&xl[ar * 512 + aphys * 8]);
#pragma unroll
    for (int dt = 0; dt < 4; ++dt) {
      const int br = dt * 16 + rloc;
      const int bphys = (u & 56) | ((u & 7) ^ (br & 7));
      const short8 bf = *reinterpret_cast<const short8*>(&wl[br * 512 + bphys * 8]);
      acc[dt] = __builtin_amdgcn_mfma_f32_16x16x32_bf16(af, bf, acc[dt], 0, 0, 0);
    }
  }

#pragma unroll
  for (int dt = 0; dt < 4; ++dt) {
    u16 us[4];
#pragma unroll
    for (int q = 0; q < 4; ++q) {
      __hip_bfloat16 bv = __float2bfloat16(acc[dt][q]);
      us[q] = *reinterpret_cast<const u16*>(&bv);
    }
    ushort4 pk = {us[0], us[1], us[2], us[3]};
    *reinterpret_cast<ushort4*>(
        WxT + (size_t)(h * HD + dt * 16 + rloc) * NN + i0 + rbase + g * 4) = pk;
  }

  float as_v[4], ad_v[4];
#pragma unroll
  for (int dt = 0; dt < 4; ++dt) {
    as_v[dt] = a[(size_t)h * 2 * HD + dt * 16 + rloc];
    ad_v[dt] = a[(size_t)h * 2 * HD + HD + dt * 16 + rloc];
  }
  float sv[4], dv[4];
#pragma unroll
  for (int q = 0; q < 4; ++q) {
    float s = 0.f, d = 0.f;
#pragma unroll
    for (int dt = 0; dt < 4; ++dt) {
      s = fmaf(acc[dt][q], as_v[dt], s);
      d = fmaf(acc[dt][q], ad_v[dt], d);
    }
    sv[q] = s; dv[q] = d;
  }
#pragma unroll
  for (int mm = 8; mm >= 1; mm >>= 1) {
#pragma unroll
    for (int q = 0; q < 4; ++q) {
      sv[q] += __shfl_xor(sv[q], mm);
      dv[q] += __shfl_xor(dv[q], mm);
    }
  }
  if (rloc == 0) {
#pragma unroll
    for (int q = 0; q < 4; ++q) {
      const int i = i0 + rbase + g * 4 + q;
      s_src[(size_t)h * NN + i] = sv[q] * LOG2E;
      d_dst[(size_t)h * NN + i] = dv[q] * LOG2E;
    }
  }
}

// ---------------------------------------------------------------------------
// K3: masked rank-1 softmax via block-local E-tables (LDS) + PV (bf16 MFMA),
// LDS-staged & double-buffered [round-15/20 verified, best config].
// grid (16 i-blocks, 4 heads, 4 j-quarters), block 512 = 8 waves x 32 rows.
// ---------------------------------------------------------------------------
__global__ __launch_bounds__(512) void k3_attn(
    const u8* __restrict__ mask,
    const u16* __restrict__ WxT,
    const float* __restrict__ s_src, const float* __restrict__ d_dst,
    u16* __restrict__ Pp, float* __restrict__ Sp)
{
  const int bx = blockIdx.x;
  const int h = blockIdx.y;
  const int jq = blockIdx.z;
  const int t = threadIdx.x;
  const int wv = t >> 6;
  const int lane = t & 63;
  const int rloc = lane & 15;
  const int g = lane >> 4;
  const int i_base = bx * 256 + wv * 32;

  __shared__ u16 wt[2][64 * 128];   // [buf][row*128 + unit*8], XOR-swizzled
  __shared__ u32 mk[256 * 36];      // [row][36 words] (32 used, pad 4)
  __shared__ float el[1024 * 2];    // (E1,E2) interleaved, 8 KiB

  const float md = MDC;
  const float si0 = s_src[(size_t)h * NN + i_base + rloc];
  const float si1 = s_src[(size_t)h * NN + i_base + 16 + rloc];
  const float e00 = si0 + md, e01 = si1 + md;
  const float m0 = fmaxf(e00, NEG_SLOPE * e00);
  const float m1 = fmaxf(e01, NEG_SLOPE * e01);
  const float sa0 = si0 - m0, sb0 = fmaf(NEG_SLOPE, si0, -m0);
  const float sa1 = si1 - m1, sb1 = fmaf(NEG_SLOPE, si1, -m1);
  float c1_0, c2_0, c1_1, c2_1;
  asm("v_exp_f32 %0, %1" : "=v"(c1_0) : "v"(sa0));
  asm("v_exp_f32 %0, %1" : "=v"(c2_0) : "v"(sb0));
  asm("v_exp_f32 %0, %1" : "=v"(c1_1) : "v"(sa1));
  asm("v_exp_f32 %0, %1" : "=v"(c2_1) : "v"(sb1));

  const u16* wsrc = WxT + (size_t)(h * HD) * NN + jq * 1024;

  const int r0 = t >> 4;
  const int un = t & 15;
  const int up = un ^ (r0 & 7);

#pragma unroll
  for (int p = 0; p < 2; ++p) {
    const int j = p * 512 + t;
    const float dj = d_dst[(size_t)h * NN + jq * 1024 + j];
    const float djs = dj * NEG_SLOPE;
    float e1, e2;
    asm("v_exp_f32 %0, %1" : "=v"(e1) : "v"(dj));    // 2^dj
    asm("v_exp_f32 %0, %1" : "=v"(e2) : "v"(djs));   // 2^(0.2 dj)
    el[j * 2] = e1;
    el[j * 2 + 1] = e2;
  }
#pragma unroll
  for (int k = 0; k < 4; ++k) {
    const int n = k * 512 + t;
    const int row = n >> 3;
    const int quad = n & 7;
    const uint4 mv = *reinterpret_cast<const uint4*>(
        mask + ((size_t)(bx * 256 + row) * (NN / 8)) + jq * 128 + quad * 16);
    *reinterpret_cast<uint4*>(&mk[row * 36 + quad * 4]) = mv;
  }
  {
    const uint4 s0 = *reinterpret_cast<const uint4*>(wsrc + (size_t)r0 * NN + un * 8);
    const uint4 s1 = *reinterpret_cast<const uint4*>(wsrc + (size_t)(r0 + 32) * NN + un * 8);
    *reinterpret_cast<uint4*>(&wt[0][r0 * 128 + up * 8]) = s0;
    *reinterpret_cast<uint4*>(&wt[0][(r0 + 32) * 128 + up * 8]) = s1;
  }
  __syncthreads();

  f32x4 acc0[4] = {}, acc1[4] = {};
  f32x4 accs0 = {}, accs1 = {};
  short8 ones;
#pragma unroll
  for (int e = 0; e < 8; ++e) ones[e] = (short)0x3F80;

  int buf = 0;
  for (int tile = 0; tile < 8; ++tile) {
    uint4 n0, n1;
    const bool pf = (tile < 7);
    if (pf) {
      n0 = *reinterpret_cast<const uint4*>(
          wsrc + (size_t)r0 * NN + (tile + 1) * 128 + un * 8);
      n1 = *reinterpret_cast<const uint4*>(
          wsrc + (size_t)(r0 + 32) * NN + (tile + 1) * 128 + un * 8);
    }

    const uint4 mq0 = *reinterpret_cast<const uint4*>(
        &mk[(wv * 32 + rloc) * 36 + tile * 4]);
    const uint4 mq1 = *reinterpret_cast<const uint4*>(
        &mk[(wv * 32 + 16 + rloc) * 36 + tile * 4]);
#pragma unroll
    for (int ks = 0; ks < 4; ++ks) {
      short8 bfr[4];
#pragma unroll
      for (int dt = 0; dt < 4; ++dt) {
        const int row = dt * 16 + rloc;
        const int unit = (ks * 4 + g) ^ (row & 7);
        bfr[dt] = *reinterpret_cast<const short8*>(&wt[buf][row * 128 + unit * 8]);
      }
      const int jloc = tile * 128 + ks * 32 + g * 8;
      const float* eb = &el[2 * jloc];
      const float4 Ea = *reinterpret_cast<const float4*>(eb);
      const float4 Eb = *reinterpret_cast<const float4*>(eb + 4);
      const float4 Ec = *reinterpret_cast<const float4*>(eb + 8);
      const float4 Ed = *reinterpret_cast<const float4*>(eb + 12);
      const float E1v[8] = {Ea.x, Ea.z, Eb.x, Eb.z, Ec.x, Ec.z, Ed.x, Ed.z};
      const float E2v[8] = {Ea.y, Ea.w, Eb.y, Eb.w, Ec.y, Ec.w, Ed.y, Ed.w};
      const u32 mw0 = (ks == 0) ? mq0.x : (ks == 1) ? mq0.y : (ks == 2) ? mq0.z : mq0.w;
      const u32 mw1 = (ks == 0) ? mq1.x : (ks == 1) ? mq1.y : (ks == 2) ? mq1.z : mq1.w;
      const u32 mb0 = (mw0 >> (g * 8)) & 0xffu;
      const u32 mb1 = (mw1 >> (g * 8)) & 0xffu;
      short8 af0, af1;
#pragma unroll
      for (int e = 0; e < 8; ++e) {
        float p0 = fmaxf(c1_0 * E1v[e], c2_0 * E2v[e]);
        float p1 = fmaxf(c1_1 * E1v[e], c2_1 * E2v[e]);
        p0 = (mb0 & (1u << e)) ? p0 : 0.f;
        p1 = (mb1 & (1u << e)) ? p1 : 0.f;
        __hip_bfloat16 b0 = __float2bfloat16(p0);
        __hip_bfloat16 b1 = __float2bfloat16(p1);
        af0[e] = *reinterpret_cast<const short*>(&b0);
        af1[e] = *reinterpret_cast<const short*>(&b1);
      }
#pragma unroll
      for (int dt = 0; dt < 4; ++dt) {
        acc0[dt] = __builtin_amdgcn_mfma_f32_16x16x32_bf16(af0, bfr[dt], acc0[dt], 0, 0, 0);
        acc1[dt] = __builtin_amdgcn_mfma_f32_16x16x32_bf16(af1, bfr[dt], acc1[dt], 0, 0, 0);
      }
      accs0 = __builtin_amdgcn_mfma_f32_16x16x32_bf16(af0, ones, accs0, 0, 0, 0);
      accs1 = __builtin_amdgcn_mfma_f32_16x16x32_bf16(af1, ones, accs1, 0, 0, 0);
    }

    if (pf) {
      *reinterpret_cast<uint4*>(&wt[buf ^ 1][r0 * 128 + up * 8]) = n0;
      *reinterpret_cast<uint4*>(&wt[buf ^ 1][(r0 + 32) * 128 + up * 8]) = n1;
    }
    __syncthreads();
    buf ^= 1;
  }

  u16* Pb = Pp + (size_t)jq * NN * OUT_DIM;
#pragma unroll
  for (int dt = 0; dt < 4; ++dt)
#pragma unroll
    for (int q = 0; q < 4; ++q) {
      __hip_bfloat16 v0 = __float2bfloat16(acc0[dt][q]);
      __hip_bfloat16 v1 = __float2bfloat16(acc1[dt][q]);
      Pb[(size_t)(i_base + g * 4 + q) * OUT_DIM + h * HD + dt * 16 + rloc] =
          *reinterpret_cast<const u16*>(&v0);
      Pb[(size_t)(i_base + 16 + g * 4 + q) * OUT_DIM + h * HD + dt * 16 + rloc] =
          *reinterpret_cast<const u16*>(&v1);
    }
  if (rloc == 0) {
    *reinterpret_cast<f32x4*>(&Sp[((size_t)jq * NH + h) * NN + i_base + g * 4]) = accs0;
    *reinterpret_cast<f32x4*>(&Sp[((size_t)jq * NH + h) * NN + i_base + 16 + g * 4]) = accs1;
  }
}

// ---------------------------------------------------------------------------
// K4: merge 4 j-quarter partials, normalize, ELU, LayerNorm, store.
// [round-7 verified]
// ---------------------------------------------------------------------------
__global__ __launch_bounds__(256) void k4_final(
    const u16* __restrict__ Pp, const float* __restrict__ Sp,
    const float* __restrict__ gamma, const float* __restrict__ beta,
    float* __restrict__ out)
{
  const int i0 = blockIdx.x * 16;
  const int t = threadIdx.x;
  const int wv = t >> 6;
  const int lane = t & 63;
  const int c0 = lane * 4;
  const int h = lane >> 4;

  const float4 gm = *reinterpret_cast<const float4*>(gamma + c0);
  const float4 bt = *reinterpret_cast<const float4*>(beta + c0);

  for (int rr = 0; rr < 4; ++rr) {
    const int i = i0 + wv * 4 + rr;
    float v[4] = {0.f, 0.f, 0.f, 0.f};
    float denom = 0.f;
#pragma unroll
    for (int q = 0; q < 4; ++q) {
      const ushort4 pv = *reinterpret_cast<const ushort4*>(
          Pp + (size_t)q * NN * OUT_DIM + (size_t)i * OUT_DIM + c0);
      v[0] += __uint_as_float((u32)pv.x << 16);
      v[1] += __uint_as_float((u32)pv.y << 16);
      v[2] += __uint_as_float((u32)pv.z << 16);
      v[3] += __uint_as_float((u32)pv.w << 16);
      denom += Sp[((size_t)q * NH + h) * NN + i];
    }
    const float inv = 1.f / denom;
    float sum = 0.f, sq = 0.f;
#pragma unroll
    for (int q2 = 0; q2 < 4; ++q2) {
      float xx = v[q2] * inv;
      xx = (xx > 0.f) ? xx : expm1f(xx);
      v[q2] = xx;
      sum += xx;
      sq += xx * xx;
    }
#pragma unroll
    for (int mm = 32; mm >= 1; mm >>= 1) {
      sum += __shfl_xor(sum, mm);
      sq += __shfl_xor(sq, mm);
    }
    const float mu = sum * (1.f / OUT_DIM);
    const float var = sq * (1.f / OUT_DIM) - mu * mu;
    const float rs = rsqrtf(var + LN_EPS);
    float4 o;
    o.x = (v[0] - mu) * rs * gm.x + bt.x;
    o.y = (v[1] - mu) * rs * gm.y + bt.y;
    o.z = (v[2] - mu) * rs * gm.z + bt.z;
    o.w = (v[3] - mu) * rs * gm.w + bt.w;
    *reinterpret_cast<float4*>(out + (size_t)i * OUT_DIM + c0) = o;
  }
}

extern "C" void kernel_launch(void* const* d_in, const int* in_sizes, int n_in,
                              void* d_out, int out_size, void* d_ws, size_t ws_size,
                              hipStream_t stream) {
  const float* x = (const float*)d_in[0];
  const int* adj = (const int*)d_in[1];
  const float* W = (const float*)d_in[2];
  const float* a = (const float*)d_in[3];
  const float* gamma = (const float*)d_in[4];
  const float* beta = (const float*)d_in[5];
  float* out = (float*)d_out;

  char* ws = (char*)d_ws;
  size_t off = 0;
  u16* WxT = (u16*)(ws + off);        off += (size_t)NH * HD * NN * 2;          // 2 MiB
  float* s_src = (float*)(ws + off);  off += (size_t)NH * NN * 4;               // 64 KiB
  float* d_dst = (float*)(ws + off);  off += (size_t)NH * NN * 4;               // 64 KiB
  u8* mask = (u8*)(ws + off);         off += (size_t)NN * (NN / 8);             // 2 MiB
  u16* Pp = (u16*)(ws + off);         off += (size_t)4 * NN * OUT_DIM * 2;      // 8 MiB (bf16)
  float* Sp = (float*)(ws + off);     off += (size_t)4 * NH * NN * 4;           // 256 KiB

  k1_proj<<<dim3(256), dim3(512), 0, stream>>>(x, W, a, adj, WxT, s_src,
                                               d_dst, mask);
  k3_attn<<<dim3(16, NH, 4), dim3(512), 0, stream>>>(mask, WxT, s_src, d_dst,
                                                     Pp, Sp);
  k4_final<<<dim3(256), dim3(256), 0, stream>>>(Pp, Sp, gamma, beta, out);
}